// Round 4
// baseline (73.461 us; speedup 1.0000x reference)
//
#include <hip/hip_runtime.h>
#include <math.h>

// PolyIoULoss closed-form, single fused kernel.
// Area(P∩T) via Green's theorem: each clipped edge contributes
// (t1-t0)*cross(A,r); cross(A,r) collapses to per-box constants plus offset
// corrections (components of R(psi)*tc). t0/t1 via Liang-Barsky against an
// AABB in the other box's local frame. Branchless; IEEE inf handles parallel
// edges. Reduction fused via last-block-done (agent-scope atomics), final
// sum in fixed order with double accumulation -> bitwise deterministic.

#define BS 256

__device__ __forceinline__ float lb_delta(float Ax, float Ay,
                                          float irx, float iry,
                                          float hw, float hh)
{
    // Liang-Barsky span of segment A + t*r, t in [0,1], vs |x|<=hw,|y|<=hh
    const float tA = (-hw - Ax) * irx;
    const float tB = ( hw - Ax) * irx;
    const float tC = (-hh - Ay) * iry;
    const float tD = ( hh - Ay) * iry;
    const float tx0 = fminf(tA, tB), tx1 = fmaxf(tA, tB);
    const float ty0 = fminf(tC, tD), ty1 = fmaxf(tC, tD);
    const float t0 = fmaxf(fmaxf(tx0, ty0), 0.0f);   // v_max3
    const float t1 = fminf(fminf(tx1, ty1), 1.0f);   // v_min3
    return fmaxf(t1 - t0, 0.0f);
}

__global__ __launch_bounds__(BS) void poly_iou_fused(
    const float* __restrict__ pred, const float* __restrict__ tgt,
    float* __restrict__ partials, unsigned int* __restrict__ counter,
    float* __restrict__ out, int n, int nblocks, double inv_n)
{
    const int tid = threadIdx.x;
    const int gid = blockIdx.x * BS + tid;

    float loss = 0.0f;
    if (gid < n) {
        const float* pp = pred + (long)gid * 5;
        const float* tp = tgt  + (long)gid * 5;
        const float pcx = pp[0], pcy = pp[1], pw = pp[2], ph = pp[3], phi = pp[4];
        const float tcx = tp[0] - pcx, tcy = tp[1] - pcy;   // pred-centered frame
        const float tw = tp[2], th = tp[3], psi = tp[4];

        const float a1 = 0.5f * pw, b1 = 0.5f * ph;
        const float a2 = 0.5f * tw, b2 = 0.5f * th;

        float sphi, cphi, spsi, cpsi;
        __sincosf(phi, &sphi, &cphi);
        __sincosf(psi, &spsi, &cpsi);
        // delta = psi - phi
        const float cd = cpsi * cphi + spsi * sphi;
        const float sd = spsi * cphi - cpsi * sphi;

        // ---- P edges in T-local frame; clipper AABB (a2,b2) ----
        const float Cx = cpsi * tcx - spsi * tcy;
        const float Cy = spsi * tcx + cpsi * tcy;
        const float Xx = a1 * cd,  Xy = a1 * sd;
        const float Yx = -b1 * sd, Yy = b1 * cd;
        const float i0x = __builtin_amdgcn_rcpf(2.0f * Xx);
        const float i0y = __builtin_amdgcn_rcpf(2.0f * Xy);
        const float i1x = __builtin_amdgcn_rcpf(2.0f * Yx);
        const float i1y = __builtin_amdgcn_rcpf(2.0f * Yy);

        const float dP0 = lb_delta(-Xx - Yx - Cx, -Xy - Yy - Cy,  i0x,  i0y, a2, b2);
        const float dP1 = lb_delta( Xx - Yx - Cx,  Xy - Yy - Cy,  i1x,  i1y, a2, b2);
        const float dP2 = lb_delta( Xx + Yx - Cx,  Xy + Yy - Cy, -i0x, -i0y, a2, b2);
        const float dP3 = lb_delta(-Xx + Yx - Cx, -Xy + Yy - Cy, -i1x, -i1y, a2, b2);
        const float sumP = (dP0 + dP1) + (dP2 + dP3);

        // ---- T edges in P-local frame; clipper AABB (a1,b1) ----
        const float C2x = cphi * tcx - sphi * tcy;
        const float C2y = sphi * tcx + cphi * tcy;
        const float Xpx = a2 * cd,  Xpy = -a2 * sd;
        const float Ypx = b2 * sd,  Ypy = b2 * cd;
        const float j0x = __builtin_amdgcn_rcpf(2.0f * Xpx);
        const float j0y = __builtin_amdgcn_rcpf(2.0f * Xpy);
        const float j1x = __builtin_amdgcn_rcpf(2.0f * Ypx);
        const float j1y = __builtin_amdgcn_rcpf(2.0f * Ypy);

        const float dT0 = lb_delta(C2x - Xpx - Ypx, C2y - Xpy - Ypy,  j0x,  j0y, a1, b1);
        const float dT1 = lb_delta(C2x + Xpx - Ypx, C2y + Xpy - Ypy,  j1x,  j1y, a1, b1);
        const float dT2 = lb_delta(C2x + Xpx + Ypx, C2y + Xpy + Ypy, -j0x, -j0y, a1, b1);
        const float dT3 = lb_delta(C2x - Xpx + Ypx, C2y - Xpy + Ypy, -j1x, -j1y, a1, b1);
        const float sumT = (dT0 + dT1) + (dT2 + dT3);

        float area = a1 * b1 * sumP + a2 * b2 * sumT
                   - a2 * Cy * (dT0 - dT2) + b2 * Cx * (dT1 - dT3);
        area = fmaxf(area, 0.0f);

        const float A1 = pw * ph, A2 = tw * th;
        const float iou = fmaxf(area / (A1 + A2 - area + 1e-6f), 1e-6f);
        loss = -__logf(iou);
    }

    // block reduction (wave shuffle + tiny LDS), deterministic
#pragma unroll
    for (int off = 32; off > 0; off >>= 1) loss += __shfl_down(loss, off);
    __shared__ float wsum[BS / 64];
    __shared__ int last_flag;
    if ((tid & 63) == 0) wsum[tid >> 6] = loss;
    __syncthreads();
    if (tid == 0) {
        float s = 0.0f;
#pragma unroll
        for (int w = 0; w < BS / 64; ++w) s += wsum[w];
        // release this block's partial, then count in at device (agent) scope.
        __hip_atomic_store(&partials[blockIdx.x], s, __ATOMIC_RELEASE,
                           __HIP_MEMORY_SCOPE_AGENT);
        const unsigned old = __hip_atomic_fetch_add(counter, 1u, __ATOMIC_ACQ_REL,
                                                    __HIP_MEMORY_SCOPE_AGENT);
        last_flag = (old == (unsigned)(nblocks - 1));
    }
    __syncthreads();

    if (last_flag) {
        // final reduction: fixed traversal order + double accumulation
        // -> bitwise-identical result regardless of which block runs it.
        double s = 0.0;
        for (int i = tid; i < nblocks; i += BS)
            s += (double)__hip_atomic_load(&partials[i], __ATOMIC_RELAXED,
                                           __HIP_MEMORY_SCOPE_AGENT);
#pragma unroll
        for (int off = 32; off > 0; off >>= 1) s += __shfl_down(s, off);
        __shared__ double ws[BS / 64];
        if ((tid & 63) == 0) ws[tid >> 6] = s;
        __syncthreads();
        if (tid == 0) {
            double tot = 0.0;
#pragma unroll
            for (int w = 0; w < BS / 64; ++w) tot += ws[w];
            out[0] = (float)(tot * inv_n);
            // leave counter clean for the next call (memset also covers it)
            __hip_atomic_store(counter, 0u, __ATOMIC_RELAXED,
                               __HIP_MEMORY_SCOPE_AGENT);
        }
    }
}

extern "C" void kernel_launch(void* const* d_in, const int* in_sizes, int n_in,
                              void* d_out, int out_size, void* d_ws, size_t ws_size,
                              hipStream_t stream) {
    const float* pred = (const float*)d_in[0];
    const float* tgt  = (const float*)d_in[1];
    float* out = (float*)d_out;
    const int n = in_sizes[0] / 5;
    const int nblocks = (n + BS - 1) / BS;

    float* partials = (float*)d_ws;
    unsigned int* counter = (unsigned int*)((char*)d_ws + ((size_t)nblocks * 4 + 255 & ~(size_t)255));

    // counter must be 0 at kernel start on EVERY call (ws is poisoned once
    // before timing and never re-poisoned; memset is graph-capture-legal).
    hipMemsetAsync(counter, 0, sizeof(unsigned int), stream);

    hipLaunchKernelGGL(poly_iou_fused, dim3(nblocks), dim3(BS), 0, stream,
                       pred, tgt, partials, counter, out, n, nblocks,
                       1.0 / (double)n);
}

// Round 5
// 12.605 us; speedup vs baseline: 5.8278x; 5.8278x over previous
//
#include <hip/hip_runtime.h>
#include <math.h>

// PolyIoULoss closed-form, two-kernel (fused last-block-done reduction was a
// 5x regression: per-block agent-scope release/acquire = cross-XCD L2
// writebacks x2048, ~60us of coherence traffic. Two dispatches are cheaper.)
//
// Area(P∩T) via Green's theorem: each clipped edge contributes
// (t1-t0)*cross(A,r); cross(A,r) collapses to per-box constants plus offset
// corrections (components of R(psi)*tc). t0/t1 via Liang-Barsky against an
// AABB in the other box's local frame. Branchless; IEEE inf handles parallel
// edges. 4 items/thread for ILP. Deterministic two-stage reduction.

#define BS 256
#define ITEMS 4

__device__ __forceinline__ float lb_delta(float Ax, float Ay,
                                          float irx, float iry,
                                          float hw, float hh)
{
    // Liang-Barsky span of segment A + t*r, t in [0,1], vs |x|<=hw,|y|<=hh
    const float tA = (-hw - Ax) * irx;
    const float tB = ( hw - Ax) * irx;
    const float tC = (-hh - Ay) * iry;
    const float tD = ( hh - Ay) * iry;
    const float tx0 = fminf(tA, tB), tx1 = fmaxf(tA, tB);
    const float ty0 = fminf(tC, tD), ty1 = fmaxf(tC, tD);
    const float t0 = fmaxf(fmaxf(tx0, ty0), 0.0f);   // v_max3
    const float t1 = fminf(fminf(tx1, ty1), 1.0f);   // v_min3
    return fmaxf(t1 - t0, 0.0f);
}

__device__ __forceinline__ float pair_loss(const float* __restrict__ pp,
                                           const float* __restrict__ tp)
{
    const float pcx = pp[0], pcy = pp[1], pw = pp[2], ph = pp[3], phi = pp[4];
    const float tcx = tp[0] - pcx, tcy = tp[1] - pcy;   // pred-centered frame
    const float tw = tp[2], th = tp[3], psi = tp[4];

    const float a1 = 0.5f * pw, b1 = 0.5f * ph;
    const float a2 = 0.5f * tw, b2 = 0.5f * th;

    float sphi, cphi, spsi, cpsi;
    __sincosf(phi, &sphi, &cphi);
    __sincosf(psi, &spsi, &cpsi);
    // delta = psi - phi
    const float cd = cpsi * cphi + spsi * sphi;
    const float sd = spsi * cphi - cpsi * sphi;

    // ---- P edges in T-local frame; clipper AABB (a2,b2) ----
    const float Cx = cpsi * tcx - spsi * tcy;
    const float Cy = spsi * tcx + cpsi * tcy;
    const float Xx = a1 * cd,  Xy = a1 * sd;
    const float Yx = -b1 * sd, Yy = b1 * cd;
    const float i0x = __builtin_amdgcn_rcpf(2.0f * Xx);
    const float i0y = __builtin_amdgcn_rcpf(2.0f * Xy);
    const float i1x = __builtin_amdgcn_rcpf(2.0f * Yx);
    const float i1y = __builtin_amdgcn_rcpf(2.0f * Yy);

    const float dP0 = lb_delta(-Xx - Yx - Cx, -Xy - Yy - Cy,  i0x,  i0y, a2, b2);
    const float dP1 = lb_delta( Xx - Yx - Cx,  Xy - Yy - Cy,  i1x,  i1y, a2, b2);
    const float dP2 = lb_delta( Xx + Yx - Cx,  Xy + Yy - Cy, -i0x, -i0y, a2, b2);
    const float dP3 = lb_delta(-Xx + Yx - Cx, -Xy + Yy - Cy, -i1x, -i1y, a2, b2);
    const float sumP = (dP0 + dP1) + (dP2 + dP3);

    // ---- T edges in P-local frame; clipper AABB (a1,b1) ----
    const float C2x = cphi * tcx - sphi * tcy;
    const float C2y = sphi * tcx + cphi * tcy;
    const float Xpx = a2 * cd,  Xpy = -a2 * sd;
    const float Ypx = b2 * sd,  Ypy = b2 * cd;
    const float j0x = __builtin_amdgcn_rcpf(2.0f * Xpx);
    const float j0y = __builtin_amdgcn_rcpf(2.0f * Xpy);
    const float j1x = __builtin_amdgcn_rcpf(2.0f * Ypx);
    const float j1y = __builtin_amdgcn_rcpf(2.0f * Ypy);

    const float dT0 = lb_delta(C2x - Xpx - Ypx, C2y - Xpy - Ypy,  j0x,  j0y, a1, b1);
    const float dT1 = lb_delta(C2x + Xpx - Ypx, C2y + Xpy - Ypy,  j1x,  j1y, a1, b1);
    const float dT2 = lb_delta(C2x + Xpx + Ypx, C2y + Xpy + Ypy, -j0x, -j0y, a1, b1);
    const float dT3 = lb_delta(C2x - Xpx + Ypx, C2y - Xpy + Ypy, -j1x, -j1y, a1, b1);
    const float sumT = (dT0 + dT1) + (dT2 + dT3);

    float area = a1 * b1 * sumP + a2 * b2 * sumT
               - a2 * Cy * (dT0 - dT2) + b2 * Cx * (dT1 - dT3);
    area = fmaxf(area, 0.0f);

    const float A1 = pw * ph, A2 = tw * th;
    const float iou = fmaxf(area / (A1 + A2 - area + 1e-6f), 1e-6f);
    return -__logf(iou);
}

__global__ __launch_bounds__(BS) void poly_iou_kernel(
    const float* __restrict__ pred, const float* __restrict__ tgt,
    float* __restrict__ block_sums, int n)
{
    const int tid = threadIdx.x;
    const int stride = gridDim.x * BS;   // threads in grid

    float loss = 0.0f;
#pragma unroll
    for (int it = 0; it < ITEMS; ++it) {
        const int gid = blockIdx.x * BS + tid + it * stride;
        if (gid < n)
            loss += pair_loss(pred + (long)gid * 5, tgt + (long)gid * 5);
    }

    // block reduction (wave shuffle + tiny LDS), deterministic
#pragma unroll
    for (int off = 32; off > 0; off >>= 1) loss += __shfl_down(loss, off);
    __shared__ float wsum[BS / 64];
    if ((tid & 63) == 0) wsum[tid >> 6] = loss;
    __syncthreads();
    if (tid == 0) {
        float s = 0.0f;
#pragma unroll
        for (int w = 0; w < BS / 64; ++w) s += wsum[w];
        block_sums[blockIdx.x] = s;
    }
}

__global__ __launch_bounds__(BS) void poly_iou_reduce(
    const float* __restrict__ block_sums, int nblocks,
    float* __restrict__ out, double inv_n)
{
    const int tid = threadIdx.x;
    double s = 0.0;
    for (int i = tid; i < nblocks; i += BS) s += (double)block_sums[i];
#pragma unroll
    for (int off = 32; off > 0; off >>= 1) s += __shfl_down(s, off);
    __shared__ double ws[BS / 64];
    if ((tid & 63) == 0) ws[tid >> 6] = s;
    __syncthreads();
    if (tid == 0) {
        double tot = 0.0;
#pragma unroll
        for (int w = 0; w < BS / 64; ++w) tot += ws[w];
        out[0] = (float)(tot * inv_n);
    }
}

extern "C" void kernel_launch(void* const* d_in, const int* in_sizes, int n_in,
                              void* d_out, int out_size, void* d_ws, size_t ws_size,
                              hipStream_t stream) {
    const float* pred = (const float*)d_in[0];
    const float* tgt  = (const float*)d_in[1];
    float* out = (float*)d_out;
    const int n = in_sizes[0] / 5;
    const int nblocks = (n + BS * ITEMS - 1) / (BS * ITEMS);
    float* bsums = (float*)d_ws;

    hipLaunchKernelGGL(poly_iou_kernel, dim3(nblocks), dim3(BS), 0, stream,
                       pred, tgt, bsums, n);
    hipLaunchKernelGGL(poly_iou_reduce, dim3(1), dim3(BS), 0, stream,
                       bsums, nblocks, out, 1.0 / (double)n);
}